// Round 1
// baseline (3741.103 us; speedup 1.0000x reference)
//
#include <hip/hip_runtime.h>
#include <cstdint>
#include <cstddef>

// ---------------------------------------------------------------------------
// NodeLayer1: 4x GATv2 conv -> fuse GEMM -> edge LN+MLP -> gather
// Dims: N=50000, D=128, H=16, C=8 (H*C=128), E1=E2=500000, E3=250000, E4=125000
// Outputs (flat, fp32): xf [N,128], edge_attr_new [E1,128], dual_out [400000,128]
// ---------------------------------------------------------------------------

#define NEG_SLOPE 0.2f

// ordered-uint encoding so unsigned atomicMax == float max
__device__ __forceinline__ unsigned fenc(float f) {
  unsigned u = __float_as_uint(f);
  return (u & 0x80000000u) ? ~u : (u | 0x80000000u);
}
__device__ __forceinline__ float fdec(unsigned k) {
  unsigned u = (k & 0x80000000u) ? (k & 0x7FFFFFFFu) : ~k;
  return __uint_as_float(u);
}

// ---------------------------------------------------------------------------
// out[M,128] = A[M,128] @ W[128,128]  (optionally +biasA added to A elements,
// optionally accumulated into out). 8 rows per block, 128 threads (1 col each).
// ---------------------------------------------------------------------------
__global__ __launch_bounds__(128) void gemm_rows8_128(
    const float* __restrict__ A, const float* __restrict__ W,
    const float* __restrict__ biasA, float* __restrict__ out,
    int M, int accumulate)
{
  __shared__ __align__(16) float lds[8 * 128];
  const int t = threadIdx.x;
  const int row0 = blockIdx.x * 8;
#pragma unroll
  for (int r = 0; r < 8; ++r) {
    int row = row0 + r;
    float v = 0.f;
    if (row < M) {
      v = A[(size_t)row * 128 + t];
      if (biasA) v += biasA[t];
    }
    lds[r * 128 + t] = v;
  }
  __syncthreads();
  float acc[8] = {0.f, 0.f, 0.f, 0.f, 0.f, 0.f, 0.f, 0.f};
  for (int k = 0; k < 128; k += 4) {
    float w0 = W[(k + 0) * 128 + t];
    float w1 = W[(k + 1) * 128 + t];
    float w2 = W[(k + 2) * 128 + t];
    float w3 = W[(k + 3) * 128 + t];
#pragma unroll
    for (int r = 0; r < 8; ++r) {
      const float4 v = *(const float4*)&lds[r * 128 + k];
      acc[r] += v.x * w0 + v.y * w1 + v.z * w2 + v.w * w3;
    }
  }
#pragma unroll
  for (int r = 0; r < 8; ++r) {
    int row = row0 + r;
    if (row < M) {
      size_t o = (size_t)row * 128 + t;
      out[o] = accumulate ? (out[o] + acc[r]) : acc[r];
    }
  }
}

// ---------------------------------------------------------------------------
// conv1 logits: m = xl[src] + xr[dst] + dual_attr[e] @ We ; leaky_relu; dot att
// 16 edges per block, 128 threads. Writes raw logits to ebuf[e*16+h] and
// atomicMax into nmax[dst*16+h].
// ---------------------------------------------------------------------------
__global__ __launch_bounds__(128) void logits_conv1(
    const float* __restrict__ xl, const float* __restrict__ xr,
    const int* __restrict__ src, const int* __restrict__ dst,
    const float* __restrict__ dualA, const float* __restrict__ We,
    const float* __restrict__ att,
    float* __restrict__ ebuf, unsigned* __restrict__ nmax, int E)
{
  __shared__ __align__(16) float lds[16 * 128];
  __shared__ int sidx[16], didx[16];
  const int t = threadIdx.x;
  const int e0 = blockIdx.x * 16;

  for (int r = 0; r < 16; ++r) {
    int e = e0 + r;
    lds[r * 128 + t] = (e < E) ? dualA[(size_t)e * 128 + t] : 0.f;
  }
  if (t < 16) {
    int e = e0 + t;
    sidx[t] = (e < E) ? src[e] : 0;
    didx[t] = (e < E) ? dst[e] : 0;
  }
  __syncthreads();

  float acc[16];
#pragma unroll
  for (int r = 0; r < 16; ++r) acc[r] = 0.f;
  for (int k = 0; k < 128; k += 4) {
    float w0 = We[(k + 0) * 128 + t];
    float w1 = We[(k + 1) * 128 + t];
    float w2 = We[(k + 2) * 128 + t];
    float w3 = We[(k + 3) * 128 + t];
#pragma unroll
    for (int r = 0; r < 16; ++r) {
      const float4 v = *(const float4*)&lds[r * 128 + k];
      acc[r] += v.x * w0 + v.y * w1 + v.z * w2 + v.w * w3;
    }
  }

  const float a_t = att[t];
  const int h = t >> 3;
  for (int r = 0; r < 16; ++r) {
    int e = e0 + r;
    if (e >= E) break;
    float m = acc[r] + xl[(size_t)sidx[r] * 128 + t] + xr[(size_t)didx[r] * 128 + t];
    float lr = (m > 0.f) ? m : NEG_SLOPE * m;
    float v = lr * a_t;
    v += __shfl_down(v, 4, 8);
    v += __shfl_down(v, 2, 8);
    v += __shfl_down(v, 1, 8);
    if ((t & 7) == 0) {
      ebuf[(size_t)e * 16 + h] = v;
      atomicMax(&nmax[(size_t)didx[r] * 16 + h], fenc(v));
    }
  }
}

// ---------------------------------------------------------------------------
// conv2..4 logits (no edge attr). One edge per block (128 threads).
// ---------------------------------------------------------------------------
__global__ __launch_bounds__(128) void logits_plain(
    const float* __restrict__ xl, const float* __restrict__ xr,
    const int* __restrict__ src, const int* __restrict__ dst,
    const float* __restrict__ att,
    float* __restrict__ ebuf, unsigned* __restrict__ nmax, int E)
{
  const int e = blockIdx.x;
  const int t = threadIdx.x;
  const int s = src[e], d = dst[e];
  float m = xl[(size_t)s * 128 + t] + xr[(size_t)d * 128 + t];
  float lr = (m > 0.f) ? m : NEG_SLOPE * m;
  float v = lr * att[t];
  v += __shfl_down(v, 4, 8);
  v += __shfl_down(v, 2, 8);
  v += __shfl_down(v, 1, 8);
  if ((t & 7) == 0) {
    int h = t >> 3;
    ebuf[(size_t)e * 16 + h] = v;
    atomicMax(&nmax[(size_t)d * 16 + h], fenc(v));
  }
}

// ---------------------------------------------------------------------------
// exp(logit - max[dst]) in place, atomicAdd into nsum. one thread per (e,h)
// ---------------------------------------------------------------------------
__global__ __launch_bounds__(256) void exp_sum(
    const int* __restrict__ dst, float* __restrict__ ebuf,
    const unsigned* __restrict__ nmax, float* __restrict__ nsum, int E)
{
  int i = blockIdx.x * 256 + threadIdx.x;
  if (i >= E * 16) return;
  int e = i >> 4, h = i & 15;
  int d = dst[e];
  float m = fdec(nmax[(size_t)d * 16 + h]);
  float ex = expf(ebuf[i] - m);
  ebuf[i] = ex;
  atomicAdd(&nsum[(size_t)d * 16 + h], ex);
}

// ---------------------------------------------------------------------------
// xc[dst] += alpha * xl[src]. one thread per (e, feature t).
// ---------------------------------------------------------------------------
__global__ __launch_bounds__(256) void aggregate(
    const int* __restrict__ src, const int* __restrict__ dst,
    const float* __restrict__ ebuf, const float* __restrict__ nsum,
    const float* __restrict__ xl, float* __restrict__ xc, int E)
{
  long long i = (long long)blockIdx.x * 256 + threadIdx.x;
  if (i >= (long long)E * 128) return;
  int e = (int)(i >> 7), t = (int)(i & 127), h = t >> 3;
  int s = src[e], d = dst[e];
  float alpha = ebuf[(size_t)e * 16 + h] / (nsum[(size_t)d * 16 + h] + 1e-16f);
  atomicAdd(&xc[(size_t)d * 128 + t], alpha * xl[(size_t)s * 128 + t]);
}

// ---------------------------------------------------------------------------
// xf init: xf[i] = fuse_b[i%128]
// ---------------------------------------------------------------------------
__global__ __launch_bounds__(256) void init_xf(
    float* __restrict__ xf, const float* __restrict__ fb, int total)
{
  int i = blockIdx.x * 256 + threadIdx.x;
  if (i < total) xf[i] = fb[i & 127];
}

// ---------------------------------------------------------------------------
// edge MLP: pair = [xf[src], xf[dst]] (256), LN, relu, @ mlp_W[256,128]+b,
// out = edge_attr + result. 16 edges per block, 128 threads.
// ---------------------------------------------------------------------------
__global__ __launch_bounds__(128) void edge_mlp(
    const float* __restrict__ xf,
    const int* __restrict__ src, const int* __restrict__ dst,
    const float* __restrict__ ln_g, const float* __restrict__ ln_b,
    const float* __restrict__ mlpW, const float* __restrict__ mlp_b,
    const float* __restrict__ edge_attr, float* __restrict__ out, int E)
{
  __shared__ __align__(16) float lds[16 * 256];
  __shared__ int sidx[16], didx[16];
  const int t = threadIdx.x;
  const int e0 = blockIdx.x * 16;
  if (t < 16) {
    int e = e0 + t;
    sidx[t] = (e < E) ? src[e] : 0;
    didx[t] = (e < E) ? dst[e] : 0;
  }
  __syncthreads();
  for (int r = 0; r < 16; ++r) {
    int e = e0 + r;
    if (e < E) {
      lds[r * 256 + t]       = xf[(size_t)sidx[r] * 128 + t];
      lds[r * 256 + 128 + t] = xf[(size_t)didx[r] * 128 + t];
    } else {
      lds[r * 256 + t] = 0.f;
      lds[r * 256 + 128 + t] = 0.f;
    }
  }
  __syncthreads();

  // per-edge layernorm: group g (of 8 lanes) handles edge g
  {
    const int g = t >> 3, j = t & 7;
    float s = 0.f, sq = 0.f;
    for (int i = 0; i < 32; ++i) {
      float v = lds[g * 256 + j + 8 * i];
      s += v; sq += v * v;
    }
    for (int off = 4; off; off >>= 1) {
      s  += __shfl_down(s,  off, 8);
      sq += __shfl_down(sq, off, 8);
    }
    s  = __shfl(s, 0, 8);
    sq = __shfl(sq, 0, 8);
    float mu = s * (1.f / 256.f);
    float var = sq * (1.f / 256.f) - mu * mu;
    float rs = rsqrtf(var + 1e-5f);
    for (int i = 0; i < 32; ++i) {
      int idx = j + 8 * i;
      float v = lds[g * 256 + idx];
      v = (v - mu) * rs * ln_g[idx] + ln_b[idx];
      lds[g * 256 + idx] = v > 0.f ? v : 0.f;
    }
  }
  __syncthreads();

  float acc[16];
#pragma unroll
  for (int r = 0; r < 16; ++r) acc[r] = 0.f;
  for (int k = 0; k < 256; k += 4) {
    float w0 = mlpW[(k + 0) * 128 + t];
    float w1 = mlpW[(k + 1) * 128 + t];
    float w2 = mlpW[(k + 2) * 128 + t];
    float w3 = mlpW[(k + 3) * 128 + t];
#pragma unroll
    for (int r = 0; r < 16; ++r) {
      const float4 v = *(const float4*)&lds[r * 256 + k];
      acc[r] += v.x * w0 + v.y * w1 + v.z * w2 + v.w * w3;
    }
  }
  const float mb = mlp_b[t];
  for (int r = 0; r < 16; ++r) {
    int e = e0 + r;
    if (e < E)
      out[(size_t)e * 128 + t] = edge_attr[(size_t)e * 128 + t] + acc[r] + mb;
  }
}

// ---------------------------------------------------------------------------
// dual_out[i] = (oemap[i] < E) ? edge_attr_new[oemap[i]] : ones
// ---------------------------------------------------------------------------
__global__ __launch_bounds__(256) void gather_dual(
    const int* __restrict__ idx, const float* __restrict__ ean,
    float* __restrict__ out, int M, int E)
{
  long long i = (long long)blockIdx.x * 256 + threadIdx.x;
  if (i >= (long long)M * 128) return;
  int row = (int)(i >> 7), t = (int)(i & 127);
  int r = idx[row];
  out[i] = (r < E) ? ean[(size_t)r * 128 + t] : 1.0f;
}

// ---------------------------------------------------------------------------

extern "C" void kernel_launch(void* const* d_in, const int* in_sizes, int n_in,
                              void* d_out, int out_size, void* d_ws, size_t ws_size,
                              hipStream_t stream)
{
  const float* x         = (const float*)d_in[0];
  const int*   ei[4]     = {(const int*)d_in[1], (const int*)d_in[2],
                            (const int*)d_in[3], (const int*)d_in[4]};
  const float* dual_attr = (const float*)d_in[5];
  const float* edge_attr = (const float*)d_in[6];
  const int*   oemap     = (const int*)d_in[7];
  const float* Wl[4]  = {(const float*)d_in[8],  (const float*)d_in[12],
                         (const float*)d_in[16], (const float*)d_in[20]};
  const float* Wr[4]  = {(const float*)d_in[9],  (const float*)d_in[13],
                         (const float*)d_in[17], (const float*)d_in[21]};
  const float* att[4] = {(const float*)d_in[10], (const float*)d_in[14],
                         (const float*)d_in[18], (const float*)d_in[22]};
  const float* bc[4]  = {(const float*)d_in[11], (const float*)d_in[15],
                         (const float*)d_in[19], (const float*)d_in[23]};
  const float* We1    = (const float*)d_in[24];
  const float* fuse_W = (const float*)d_in[25];
  const float* fuse_b = (const float*)d_in[26];
  const float* ln_g   = (const float*)d_in[27];
  const float* ln_b   = (const float*)d_in[28];
  const float* mlp_W  = (const float*)d_in[29];
  const float* mlp_b  = (const float*)d_in[30];

  const int N  = in_sizes[0] / 128;
  int E[4];
  for (int c = 0; c < 4; ++c) E[c] = in_sizes[1 + c] / 2;
  const int Moe = in_sizes[7];

  // workspace layout (floats)
  float* ws    = (float*)d_ws;
  float* xl    = ws;                       // N*128
  float* xr    = xl + (size_t)N * 128;     // N*128
  float* xc    = xr + (size_t)N * 128;     // N*128
  float* ebuf  = xc + (size_t)N * 128;     // Emax*16
  unsigned* nmax = (unsigned*)(ebuf + (size_t)E[0] * 16); // N*16
  float* nsum  = (float*)(nmax + (size_t)N * 16);         // N*16

  // output layout
  float* xf      = (float*)d_out;                 // N*128
  float* ean     = xf + (size_t)N * 128;          // E1*128
  float* dualout = ean + (size_t)E[0] * 128;      // Moe*128

  const int rowBlocks = (N + 7) / 8;

  // xf = fuse_b (accumulated into below)
  init_xf<<<(N * 128 + 255) / 256, 256, 0, stream>>>(xf, fuse_b, N * 128);

  for (int c = 0; c < 4; ++c) {
    const int* src = ei[c];
    const int* dst = ei[c] + E[c];

    gemm_rows8_128<<<rowBlocks, 128, 0, stream>>>(x, Wl[c], nullptr, xl, N, 0);
    gemm_rows8_128<<<rowBlocks, 128, 0, stream>>>(x, Wr[c], nullptr, xr, N, 0);

    hipMemsetAsync(xc,   0, (size_t)N * 128 * sizeof(float), stream);
    hipMemsetAsync(nmax, 0, (size_t)N * 16 * sizeof(unsigned), stream);
    hipMemsetAsync(nsum, 0, (size_t)N * 16 * sizeof(float), stream);

    if (c == 0) {
      logits_conv1<<<(E[c] + 15) / 16, 128, 0, stream>>>(
          xl, xr, src, dst, dual_attr, We1, att[c], ebuf, nmax, E[c]);
    } else {
      logits_plain<<<E[c], 128, 0, stream>>>(
          xl, xr, src, dst, att[c], ebuf, nmax, E[c]);
    }

    exp_sum<<<(E[c] * 16 + 255) / 256, 256, 0, stream>>>(dst, ebuf, nmax, nsum, E[c]);

    aggregate<<<(int)(((long long)E[c] * 128 + 255) / 256), 256, 0, stream>>>(
        src, dst, ebuf, nsum, xl, xc, E[c]);

    // xf += (xc + b_c) @ fuse_W[c*128:(c+1)*128, :]
    gemm_rows8_128<<<rowBlocks, 128, 0, stream>>>(
        xc, fuse_W + (size_t)c * 128 * 128, bc[c], xf, N, 1);
  }

  edge_mlp<<<(E[0] + 15) / 16, 128, 0, stream>>>(
      xf, ei[0], ei[0] + E[0], ln_g, ln_b, mlp_W, mlp_b, edge_attr, ean, E[0]);

  gather_dual<<<(int)(((long long)Moe * 128 + 255) / 256), 256, 0, stream>>>(
      oemap, ean, dualout, Moe, E[0]);
}